// Round 7
// baseline (352.085 us; speedup 1.0000x reference)
//
#include <hip/hip_runtime.h>
#include <hip/hip_bf16.h>

// GCN 2-layer encoder. CSR-gather aggregation + LDS-free split-bf16 MFMA GEMMs.
// GEMM: A-fragments loaded directly from global (8 consecutive k/lane), converted in regs;
// B pre-transposed bf16 hi/lo in L2 — no LDS, no barriers, register double-buffer.

typedef __attribute__((ext_vector_type(4))) float f32x4;
typedef __attribute__((ext_vector_type(8))) short short8;

static __device__ __forceinline__ unsigned short f2bf(float f) {
    unsigned int u = __float_as_uint(f);
    u += 0x7FFF + ((u >> 16) & 1);          // round-to-nearest-even
    return (unsigned short)(u >> 16);
}
static __device__ __forceinline__ float bf2f(unsigned short h) {
    return __uint_as_float(((unsigned int)h) << 16);
}

__global__ void fill_int(int* __restrict__ p, int v, int n) {
    int i = blockIdx.x * blockDim.x + threadIdx.x;
    if (i < n) p[i] = v;
}

__global__ void deg_accum_i(const int* __restrict__ dst, int* __restrict__ deg, int E) {
    int i = blockIdx.x * blockDim.x + threadIdx.x;
    if (i < E) atomicAdd(&deg[dst[i]], 1);
}

__global__ void make_dis(int* __restrict__ deg, int N) {
    int i = blockIdx.x * blockDim.x + threadIdx.x;
    if (i < N) {
        int d = deg[i];
        ((float*)deg)[i] = rsqrtf((float)(d + 1));
    }
}

// ---- hierarchical exclusive scan: deg[N] -> rp[N+1], cursor[N] ----
__global__ void scan_part(const int* __restrict__ deg, int* __restrict__ bsum, int N) {
    int tid = threadIdx.x, lane = tid & 63, wid = tid >> 6;
    int i = blockIdx.x * 256 + tid;
    int v = (i < N) ? deg[i] : 0;
#pragma unroll
    for (int off = 1; off < 64; off <<= 1) v += __shfl_xor(v, off, 64);
    __shared__ int ws[4];
    if (lane == 0) ws[wid] = v;
    __syncthreads();
    if (tid == 0) bsum[blockIdx.x] = ws[0] + ws[1] + ws[2] + ws[3];
}

__global__ __launch_bounds__(1024) void scan_top(const int* __restrict__ bsum, int nb,
                                                 int* __restrict__ boff, int* __restrict__ rp, int N) {
    __shared__ int wsum[16];
    int tid = threadIdx.x, lane = tid & 63, wid = tid >> 6;
    int v = (tid < nb) ? bsum[tid] : 0;
    int x = v;
#pragma unroll
    for (int off = 1; off < 64; off <<= 1) {
        int t = __shfl_up(x, off, 64);
        if (lane >= off) x += t;
    }
    if (lane == 63) wsum[wid] = x;
    __syncthreads();
    if (tid < 16) {
        int y = wsum[tid];
#pragma unroll
        for (int off = 1; off < 16; off <<= 1) {
            int t = __shfl_up(y, off, 16);
            if (tid >= off) y += t;
        }
        wsum[tid] = y;
    }
    __syncthreads();
    int base = wid ? wsum[wid - 1] : 0;
    if (tid < nb) boff[tid] = base + x - v;
    if (tid == 0) rp[N] = wsum[15];
}

__global__ void scan_final(const int* __restrict__ deg, const int* __restrict__ boff,
                           int* __restrict__ rp, int* __restrict__ cursor, int N) {
    int tid = threadIdx.x, lane = tid & 63, wid = tid >> 6;
    int i = blockIdx.x * 256 + tid;
    int v = (i < N) ? deg[i] : 0;
    int x = v;
#pragma unroll
    for (int off = 1; off < 64; off <<= 1) {
        int t = __shfl_up(x, off, 64);
        if (lane >= off) x += t;
    }
    __shared__ int wsum[4];
    if (lane == 63) wsum[wid] = x;
    __syncthreads();
    int base = boff[blockIdx.x];
    for (int ww = 0; ww < wid; ww++) base += wsum[ww];
    int ex = base + x - v;
    if (i < N) { rp[i] = ex; cursor[i] = ex; }
}

__global__ void csr_fill(const int* __restrict__ src, const int* __restrict__ dst,
                         int* __restrict__ cursor, int* __restrict__ csr_src, int E) {
    int e = blockIdx.x * blockDim.x + threadIdx.x;
    if (e < E) {
        int pos = atomicAdd(&cursor[dst[e]], 1);
        csr_src[pos] = src[e];
    }
}

// B[K x N] f32 -> transposed bf16 hi/lo [N][Kpad] (zero-padded past K)
__global__ void prep_b(const float* __restrict__ B, unsigned short* __restrict__ Bth,
                       unsigned short* __restrict__ Btl, int K, int N, int Kpad) {
    int idx = blockIdx.x * 256 + threadIdx.x;
    if (idx >= N * Kpad) return;
    int n = idx / Kpad, k = idx - n * Kpad;
    float v = (k < K) ? B[(size_t)k * N + n] : 0.f;
    unsigned short h = f2bf(v);
    Bth[idx] = h;
    Btl[idx] = f2bf(v - bf2f(h));
}

// C[M x Nc] = A[M x K] @ B[K x Nc], split-bf16 MFMA, NO LDS / NO barriers.
// Per wave: MF*16 rows x NF*16 cols. Block = WR x WC waves (WR*WC==4).
// A-frag: lane reads 8 consecutive f32 (two guarded float4), converts to bf16 hi/lo.
// B-frag: lane reads 8 consecutive ushorts from preconverted [N][Kpad] (L2-resident).
template<int MF, int NF, int WR, int WC, int KT>
__global__ __launch_bounds__(256) void gemm_reg(
    const float* __restrict__ A, const unsigned short* __restrict__ Bth,
    const unsigned short* __restrict__ Btl, float* __restrict__ C,
    int M, int K, int Kpad, int Nc) {
    static_assert(WR * WC == 4, "4 waves per block");
    const int tid = threadIdx.x, lane = tid & 63, w = tid >> 6;
    const int wr = w / WC, wc = w % WC;
    const int lrow = lane & 15, lkq = (lane >> 4) * 8;
    const int bm = blockIdx.x * (WR * MF * 16) + wr * MF * 16;
    const int bn = wc * NF * 16;

    f32x4 acc[MF][NF] = {};

    const float* arow[MF];
    bool aok[MF];
#pragma unroll
    for (int m = 0; m < MF; m++) {
        int r = bm + m * 16 + lrow;
        aok[m] = r < M;
        arow[m] = A + (size_t)r * K;
    }
    size_t boff[NF];
#pragma unroll
    for (int n = 0; n < NF; n++) boff[n] = (size_t)(bn + n * 16 + lrow) * Kpad;

    float4 a0[MF][2], a1[MF][2];
    short8 b0h[NF], b0l[NF], b1h[NF], b1l[NF];

    auto LDA = [&](float4 (&a)[MF][2], int kt) {
        const int kg = kt * 32 + lkq;
        const float4 z = make_float4(0.f, 0.f, 0.f, 0.f);
#pragma unroll
        for (int m = 0; m < MF; m++) {
            a[m][0] = (aok[m] && kg + 4 <= K) ? *(const float4*)(arow[m] + kg) : z;
            a[m][1] = (aok[m] && kg + 8 <= K) ? *(const float4*)(arow[m] + kg + 4) : z;
        }
    };
    auto LDB = [&](short8 (&bh)[NF], short8 (&bl)[NF], int kt) {
        const int kg = kt * 32 + lkq;
#pragma unroll
        for (int n = 0; n < NF; n++) {
            bh[n] = *(const short8*)(Bth + boff[n] + kg);
            bl[n] = *(const short8*)(Btl + boff[n] + kg);
        }
    };
    auto STEP = [&](float4 (&a)[MF][2], short8 (&bh)[NF], short8 (&bl)[NF]) {
#pragma unroll
        for (int m = 0; m < MF; m++) {
            float fv[8] = {a[m][0].x, a[m][0].y, a[m][0].z, a[m][0].w,
                           a[m][1].x, a[m][1].y, a[m][1].z, a[m][1].w};
            short8 ah, al;
#pragma unroll
            for (int j = 0; j < 8; j++) {
                unsigned short hu = f2bf(fv[j]);
                ah[j] = (short)hu;
                al[j] = (short)f2bf(fv[j] - bf2f(hu));
            }
#pragma unroll
            for (int n = 0; n < NF; n++) {
                acc[m][n] = __builtin_amdgcn_mfma_f32_16x16x32_bf16(ah, bh[n], acc[m][n], 0, 0, 0);
                acc[m][n] = __builtin_amdgcn_mfma_f32_16x16x32_bf16(al, bh[n], acc[m][n], 0, 0, 0);
                acc[m][n] = __builtin_amdgcn_mfma_f32_16x16x32_bf16(ah, bl[n], acc[m][n], 0, 0, 0);
            }
        }
    };

    LDA(a0, 0);
    LDB(b0h, b0l, 0);
    for (int kt = 0; kt < KT; kt += 2) {
        LDA(a1, kt + 1); LDB(b1h, b1l, kt + 1);
        STEP(a0, b0h, b0l);
        if (kt + 2 < KT) { LDA(a0, kt + 2); LDB(b0h, b0l, kt + 2); }
        STEP(a1, b1h, b1l);
    }

    // store: C/D layout col=lane&15, row=(lane>>4)*4+q
#pragma unroll
    for (int m = 0; m < MF; m++)
#pragma unroll
        for (int n = 0; n < NF; n++)
#pragma unroll
            for (int q = 0; q < 4; q++) {
                int row = bm + m * 16 + (lane >> 4) * 4 + q;
                int col = bn + n * 16 + lrow;
                if (row < M) C[(size_t)row * Nc + col] = acc[m][n][q];
            }
}

// one wave per dst node, lanes across 128 features (float2/lane); fused self-loop+bias+relu
__global__ __launch_bounds__(256) void gather128(
    const int* __restrict__ rp, const int* __restrict__ csr,
    const float* __restrict__ dis, const float* __restrict__ h,
    const float* __restrict__ bias, float* __restrict__ out, int Nn) {
    int n = (blockIdx.x * 256 + threadIdx.x) >> 6;
    int lane = threadIdx.x & 63;
    if (n >= Nn) return;
    int beg = rp[n], end = rp[n + 1];
    float a0x = 0.f, a0y = 0.f, a1x = 0.f, a1y = 0.f;
    float a2x = 0.f, a2y = 0.f, a3x = 0.f, a3y = 0.f;
    int j = beg;
    for (; j + 3 < end; j += 4) {
        int s0 = csr[j], s1 = csr[j + 1], s2 = csr[j + 2], s3 = csr[j + 3];
        float w0 = dis[s0], w1 = dis[s1], w2 = dis[s2], w3 = dis[s3];
        float2 v0 = *(const float2*)&h[(size_t)s0 * 128 + lane * 2];
        float2 v1 = *(const float2*)&h[(size_t)s1 * 128 + lane * 2];
        float2 v2 = *(const float2*)&h[(size_t)s2 * 128 + lane * 2];
        float2 v3 = *(const float2*)&h[(size_t)s3 * 128 + lane * 2];
        a0x = fmaf(w0, v0.x, a0x); a0y = fmaf(w0, v0.y, a0y);
        a1x = fmaf(w1, v1.x, a1x); a1y = fmaf(w1, v1.y, a1y);
        a2x = fmaf(w2, v2.x, a2x); a2y = fmaf(w2, v2.y, a2y);
        a3x = fmaf(w3, v3.x, a3x); a3y = fmaf(w3, v3.y, a3y);
    }
    for (; j < end; j++) {
        int s = csr[j];
        float ww = dis[s];
        float2 v = *(const float2*)&h[(size_t)s * 128 + lane * 2];
        a0x = fmaf(ww, v.x, a0x); a0y = fmaf(ww, v.y, a0y);
    }
    float accx = (a0x + a1x) + (a2x + a3x);
    float accy = (a0y + a1y) + (a2y + a3y);
    float dn = dis[n];
    float2 hv = *(const float2*)&h[(size_t)n * 128 + lane * 2];
    float2 o;
    o.x = fmaxf(dn * (accx + dn * hv.x) + bias[lane * 2], 0.f);
    o.y = fmaxf(dn * (accy + dn * hv.y) + bias[lane * 2 + 1], 0.f);
    *(float2*)&out[(size_t)n * 128 + lane * 2] = o;
}

// one wave per dst node, lanes across 64 features; fused self-loop+bias (no relu)
__global__ __launch_bounds__(256) void gather64(
    const int* __restrict__ rp, const int* __restrict__ csr,
    const float* __restrict__ dis, const float* __restrict__ h,
    const float* __restrict__ bias, float* __restrict__ out, int Nn) {
    int n = (blockIdx.x * 256 + threadIdx.x) >> 6;
    int lane = threadIdx.x & 63;
    if (n >= Nn) return;
    int beg = rp[n], end = rp[n + 1];
    float a0 = 0.f, a1 = 0.f, a2 = 0.f, a3 = 0.f;
    int j = beg;
    for (; j + 3 < end; j += 4) {
        int s0 = csr[j], s1 = csr[j + 1], s2 = csr[j + 2], s3 = csr[j + 3];
        float w0 = dis[s0], w1 = dis[s1], w2 = dis[s2], w3 = dis[s3];
        float v0 = h[(size_t)s0 * 64 + lane];
        float v1 = h[(size_t)s1 * 64 + lane];
        float v2 = h[(size_t)s2 * 64 + lane];
        float v3 = h[(size_t)s3 * 64 + lane];
        a0 = fmaf(w0, v0, a0); a1 = fmaf(w1, v1, a1);
        a2 = fmaf(w2, v2, a2); a3 = fmaf(w3, v3, a3);
    }
    for (; j < end; j++) {
        int s = csr[j];
        a0 = fmaf(dis[s], h[(size_t)s * 64 + lane], a0);
    }
    float acc = (a0 + a1) + (a2 + a3);
    float dn = dis[n];
    float hv = h[(size_t)n * 64 + lane];
    out[(size_t)n * 64 + lane] = dn * (acc + dn * hv) + bias[lane];
}

extern "C" void kernel_launch(void* const* d_in, const int* in_sizes, int n_in,
                              void* d_out, int out_size, void* d_ws, size_t ws_size,
                              hipStream_t stream) {
    const float* x  = (const float*)d_in[0];
    const int*   ei = (const int*)d_in[1];
    const float* W1 = (const float*)d_in[2];
    const float* b1 = (const float*)d_in[3];
    const float* W2 = (const float*)d_in[4];
    const float* b2 = (const float*)d_in[5];

    const int IN = 500, H = 128, OUT = 64;
    const int Nn = in_sizes[0] / IN;     // 50000
    const int E  = in_sizes[1] / 2;      // 800000
    const int* src  = ei;
    const int* dstp = ei + E;

    const int Npad = ((Nn + 63) / 64) * 64;
    const int nb   = (Nn + 255) / 256;
    const int K1p  = 512, K2p = 128;

    // workspace layout (int units)
    int*   degdis  = (int*)d_ws;                 // N: int deg -> float dis in place
    int*   rp      = degdis + Npad;              // N+1
    int*   bsum    = rp + Npad + 64;             // 1024
    int*   boff    = bsum + 1024;                // 1024
    int*   cursor  = boff + 1024;                // N
    int*   csr_src = cursor + Npad;              // E
    unsigned short* Bt1h = (unsigned short*)(csr_src + ((E + 63) / 64) * 64);  // 128*512
    unsigned short* Bt1l = Bt1h + H * K1p;
    unsigned short* Bt2h = Bt1l + H * K1p;       // 64*128
    unsigned short* Bt2l = Bt2h + OUT * K2p;
    float* h1      = (float*)(Bt2l + OUT * K2p);
    float* agg1    = h1 + (size_t)Nn * H;
    float* h2      = h1;                         // reuse after layer-1 gather
    float* dis     = (float*)degdis;
    float* out     = (float*)d_out;

    // ---- degree / CSR build ----
    fill_int<<<(Nn + 255) / 256, 256, 0, stream>>>(degdis, 0, Nn);
    deg_accum_i<<<(E + 255) / 256, 256, 0, stream>>>(dstp, degdis, E);
    scan_part<<<nb, 256, 0, stream>>>(degdis, bsum, Nn);
    scan_top<<<1, 1024, 0, stream>>>(bsum, nb, boff, rp, Nn);
    scan_final<<<nb, 256, 0, stream>>>(degdis, boff, rp, cursor, Nn);
    make_dis<<<(Nn + 255) / 256, 256, 0, stream>>>(degdis, Nn);
    csr_fill<<<(E + 255) / 256, 256, 0, stream>>>(src, dstp, cursor, csr_src, E);

    // ---- weight prep (bf16 hi/lo, transposed) ----
    prep_b<<<(H * K1p + 255) / 256, 256, 0, stream>>>(W1, Bt1h, Bt1l, IN, H, K1p);
    prep_b<<<(OUT * K2p + 255) / 256, 256, 0, stream>>>(W2, Bt2h, Bt2l, H, OUT, K2p);

    // ---- layer 1: h1 = x @ W1 ----  per-wave 32x64, block 64 rows x 128 cols
    gemm_reg<2, 4, 2, 2, 16><<<(Nn + 63) / 64, 256, 0, stream>>>(x, Bt1h, Bt1l, h1, Nn, IN, K1p, H);
    gather128<<<(Nn + 3) / 4, 256, 0, stream>>>(rp, csr_src, dis, h1, b1, agg1, Nn);

    // ---- layer 2: h2 = agg1 @ W2 ----  per-wave 16x64, block 64 rows x 64 cols
    gemm_reg<1, 4, 4, 1, 4><<<(Nn + 63) / 64, 256, 0, stream>>>(agg1, Bt2h, Bt2l, h2, Nn, H, K2p, OUT);
    gather64<<<(Nn + 3) / 4, 256, 0, stream>>>(rp, csr_src, dis, h2, b2, out, Nn);
}

// Round 8
// 276.680 us; speedup vs baseline: 1.2725x; 1.2725x over previous
//
#include <hip/hip_runtime.h>
#include <hip/hip_bf16.h>

// GCN 2-layer encoder. CSR-gather aggregation + split-bf16 MFMA GEMMs.
// GEMM: 2-phase double-buffered LDS pipeline (reg-staged A w/ f32->bf16 hi/lo convert,
// B preconverted bf16 hi/lo in L2). One barrier per K-tile.

typedef __attribute__((ext_vector_type(4))) float f32x4;
typedef __attribute__((ext_vector_type(8))) short short8;
typedef __attribute__((ext_vector_type(8))) unsigned short u16x8;

static __device__ __forceinline__ unsigned short f2bf(float f) {
    unsigned int u = __float_as_uint(f);
    u += 0x7FFF + ((u >> 16) & 1);          // round-to-nearest-even
    return (unsigned short)(u >> 16);
}
static __device__ __forceinline__ float bf2f(unsigned short h) {
    return __uint_as_float(((unsigned int)h) << 16);
}

__global__ void fill_int(int* __restrict__ p, int v, int n) {
    int i = blockIdx.x * blockDim.x + threadIdx.x;
    if (i < n) p[i] = v;
}

__global__ void deg_accum_i(const int* __restrict__ dst, int* __restrict__ deg, int E) {
    int i = blockIdx.x * blockDim.x + threadIdx.x;
    if (i < E) atomicAdd(&deg[dst[i]], 1);
}

__global__ void make_dis(int* __restrict__ deg, int N) {
    int i = blockIdx.x * blockDim.x + threadIdx.x;
    if (i < N) {
        int d = deg[i];
        ((float*)deg)[i] = rsqrtf((float)(d + 1));
    }
}

// ---- hierarchical exclusive scan: deg[N] -> rp[N+1], cursor[N] ----
__global__ void scan_part(const int* __restrict__ deg, int* __restrict__ bsum, int N) {
    int tid = threadIdx.x, lane = tid & 63, wid = tid >> 6;
    int i = blockIdx.x * 256 + tid;
    int v = (i < N) ? deg[i] : 0;
#pragma unroll
    for (int off = 1; off < 64; off <<= 1) v += __shfl_xor(v, off, 64);
    __shared__ int ws[4];
    if (lane == 0) ws[wid] = v;
    __syncthreads();
    if (tid == 0) bsum[blockIdx.x] = ws[0] + ws[1] + ws[2] + ws[3];
}

__global__ __launch_bounds__(1024) void scan_top(const int* __restrict__ bsum, int nb,
                                                 int* __restrict__ boff, int* __restrict__ rp, int N) {
    __shared__ int wsum[16];
    int tid = threadIdx.x, lane = tid & 63, wid = tid >> 6;
    int v = (tid < nb) ? bsum[tid] : 0;
    int x = v;
#pragma unroll
    for (int off = 1; off < 64; off <<= 1) {
        int t = __shfl_up(x, off, 64);
        if (lane >= off) x += t;
    }
    if (lane == 63) wsum[wid] = x;
    __syncthreads();
    if (tid < 16) {
        int y = wsum[tid];
#pragma unroll
        for (int off = 1; off < 16; off <<= 1) {
            int t = __shfl_up(y, off, 16);
            if (tid >= off) y += t;
        }
        wsum[tid] = y;
    }
    __syncthreads();
    int base = wid ? wsum[wid - 1] : 0;
    if (tid < nb) boff[tid] = base + x - v;
    if (tid == 0) rp[N] = wsum[15];
}

__global__ void scan_final(const int* __restrict__ deg, const int* __restrict__ boff,
                           int* __restrict__ rp, int* __restrict__ cursor, int N) {
    int tid = threadIdx.x, lane = tid & 63, wid = tid >> 6;
    int i = blockIdx.x * 256 + tid;
    int v = (i < N) ? deg[i] : 0;
    int x = v;
#pragma unroll
    for (int off = 1; off < 64; off <<= 1) {
        int t = __shfl_up(x, off, 64);
        if (lane >= off) x += t;
    }
    __shared__ int wsum[4];
    if (lane == 63) wsum[wid] = x;
    __syncthreads();
    int base = boff[blockIdx.x];
    for (int ww = 0; ww < wid; ww++) base += wsum[ww];
    int ex = base + x - v;
    if (i < N) { rp[i] = ex; cursor[i] = ex; }
}

__global__ void csr_fill(const int* __restrict__ src, const int* __restrict__ dst,
                         int* __restrict__ cursor, int* __restrict__ csr_src, int E) {
    int e = blockIdx.x * blockDim.x + threadIdx.x;
    if (e < E) {
        int pos = atomicAdd(&cursor[dst[e]], 1);
        csr_src[pos] = src[e];
    }
}

// B[K x N] f32 -> transposed bf16 hi/lo [N][Kpad] (zero-padded past K)
__global__ void prep_b(const float* __restrict__ B, unsigned short* __restrict__ Bth,
                       unsigned short* __restrict__ Btl, int K, int N, int Kpad) {
    int idx = blockIdx.x * 256 + threadIdx.x;
    if (idx >= N * Kpad) return;
    int n = idx / Kpad, k = idx - n * Kpad;
    float v = (k < K) ? B[(size_t)k * N + n] : 0.f;
    unsigned short h = f2bf(v);
    Bth[idx] = h;
    Btl[idx] = f2bf(v - bf2f(h));
}

// C[M x BN] = A[M x K] @ B[K x BN], split-bf16 MFMA, 2-phase double-buffered LDS.
// Block 256 thr = 4 waves (WRxWC), tile BM x BN, BK=32, KT K-tiles (Kpad = KT*32).
template<int BM, int BN, int KT, int WR, int WC>
__global__ __launch_bounds__(256) void gemm_db(
    const float* __restrict__ A, const unsigned short* __restrict__ Bth,
    const unsigned short* __restrict__ Btl, float* __restrict__ C,
    int M, int K, int Kpad) {
    constexpr int BK = 32, STR = 40;           // 80B LDS row: 16B-aligned, pow2-breaking
    constexpr int MF = BM / WR / 16;
    constexpr int NF = BN / WC / 16;
    constexpr int APT = BM * BK / 256;         // f32 per thread (A staging)
    constexpr int AV = APT / 4;                // float4 per thread
    constexpr int TPRA = BK / APT;             // threads per A row
    constexpr int BPT = BN * BK / 256;         // u16 per thread per kind (B staging)
    constexpr int BV = BPT / 8;                // u16x8 per thread per kind
    constexpr int TPCB = BK / BPT;             // threads per B col
    static_assert(AV >= 1 && BV >= 1, "staging shape");

    __shared__ unsigned short AsH[2][BM][STR], AsL[2][BM][STR];
    __shared__ unsigned short BsH[2][BN][STR], BsL[2][BN][STR];

    const int tid = threadIdx.x;
    const int lane = tid & 63;
    const int w = tid >> 6;
    const int wrow = (w / WC) * (MF * 16);
    const int wcol = (w % WC) * (NF * 16);
    const int bm = blockIdx.x * BM;
    const int lrow = lane & 15;
    const int lkq = (lane >> 4) * 8;
    const int aRow = tid / TPRA;
    const int aKc = (tid % TPRA) * APT;
    const int bCol = tid / TPCB;
    const int bKc = (tid % TPCB) * BPT;

    const bool aOk = (bm + aRow) < M;
    const float* aPtr = A + (size_t)(bm + aRow) * K;
    const size_t bBase = (size_t)bCol * Kpad + bKc;

    f32x4 acc[MF][NF] = {};
    float4 af[AV];
    u16x8 bfh[BV], bfl[BV];

    auto ISSUE = [&](int kt) {
        const int k0 = kt * BK;
        const float4 z = make_float4(0.f, 0.f, 0.f, 0.f);
#pragma unroll
        for (int v = 0; v < AV; v++) {
            int kg = k0 + aKc + v * 4;
            af[v] = (aOk && kg + 4 <= K) ? *(const float4*)(aPtr + kg) : z;
        }
#pragma unroll
        for (int v = 0; v < BV; v++) {
            bfh[v] = *(const u16x8*)(Bth + bBase + k0 + v * 8);
            bfl[v] = *(const u16x8*)(Btl + bBase + k0 + v * 8);
        }
    };
    auto WRITE = [&](int b) {
#pragma unroll
        for (int v = 0; v < AV; v++) {
            float4 x4 = af[v];
            ushort4 h4, l4;
            h4.x = f2bf(x4.x); l4.x = f2bf(x4.x - bf2f(h4.x));
            h4.y = f2bf(x4.y); l4.y = f2bf(x4.y - bf2f(h4.y));
            h4.z = f2bf(x4.z); l4.z = f2bf(x4.z - bf2f(h4.z));
            h4.w = f2bf(x4.w); l4.w = f2bf(x4.w - bf2f(h4.w));
            *(ushort4*)&AsH[b][aRow][aKc + v * 4] = h4;
            *(ushort4*)&AsL[b][aRow][aKc + v * 4] = l4;
        }
#pragma unroll
        for (int v = 0; v < BV; v++) {
            *(u16x8*)&BsH[b][bCol][bKc + v * 8] = bfh[v];
            *(u16x8*)&BsL[b][bCol][bKc + v * 8] = bfl[v];
        }
    };
    auto COMPUTE = [&](int b) {
        short8 ah[MF], al[MF], bh2[NF], bl2[NF];
#pragma unroll
        for (int m = 0; m < MF; m++) {
            ah[m] = *(const short8*)&AsH[b][wrow + m * 16 + lrow][lkq];
            al[m] = *(const short8*)&AsL[b][wrow + m * 16 + lrow][lkq];
        }
#pragma unroll
        for (int n = 0; n < NF; n++) {
            bh2[n] = *(const short8*)&BsH[b][wcol + n * 16 + lrow][lkq];
            bl2[n] = *(const short8*)&BsL[b][wcol + n * 16 + lrow][lkq];
        }
#pragma unroll
        for (int m = 0; m < MF; m++)
#pragma unroll
            for (int n = 0; n < NF; n++) {
                acc[m][n] = __builtin_amdgcn_mfma_f32_16x16x32_bf16(ah[m], bh2[n], acc[m][n], 0, 0, 0);
                acc[m][n] = __builtin_amdgcn_mfma_f32_16x16x32_bf16(al[m], bh2[n], acc[m][n], 0, 0, 0);
                acc[m][n] = __builtin_amdgcn_mfma_f32_16x16x32_bf16(ah[m], bl2[n], acc[m][n], 0, 0, 0);
            }
    };

    ISSUE(0);
    WRITE(0);
    __syncthreads();
    int cur = 0;
    for (int kt = 0; kt < KT; kt++) {
        const bool more = (kt + 1 < KT);
        if (more) ISSUE(kt + 1);     // global loads in flight under compute
        COMPUTE(cur);
        if (more) WRITE(cur ^ 1);    // convert + stage next tile
        __syncthreads();
        cur ^= 1;
    }

    // store: C/D layout col=lane&15, row=(lane>>4)*4+q
#pragma unroll
    for (int m = 0; m < MF; m++)
#pragma unroll
        for (int n = 0; n < NF; n++)
#pragma unroll
            for (int q = 0; q < 4; q++) {
                int row = bm + wrow + m * 16 + (lane >> 4) * 4 + q;
                int col = wcol + n * 16 + lrow;
                if (row < M) C[(size_t)row * BN + col] = acc[m][n][q];
            }
}

// one wave per dst node, lanes across 128 features (float2/lane); fused self-loop+bias+relu
__global__ __launch_bounds__(256) void gather128(
    const int* __restrict__ rp, const int* __restrict__ csr,
    const float* __restrict__ dis, const float* __restrict__ h,
    const float* __restrict__ bias, float* __restrict__ out, int Nn) {
    int n = (blockIdx.x * 256 + threadIdx.x) >> 6;
    int lane = threadIdx.x & 63;
    if (n >= Nn) return;
    int beg = rp[n], end = rp[n + 1];
    float a0x = 0.f, a0y = 0.f, a1x = 0.f, a1y = 0.f;
    float a2x = 0.f, a2y = 0.f, a3x = 0.f, a3y = 0.f;
    int j = beg;
    for (; j + 3 < end; j += 4) {
        int s0 = csr[j], s1 = csr[j + 1], s2 = csr[j + 2], s3 = csr[j + 3];
        float w0 = dis[s0], w1 = dis[s1], w2 = dis[s2], w3 = dis[s3];
        float2 v0 = *(const float2*)&h[(size_t)s0 * 128 + lane * 2];
        float2 v1 = *(const float2*)&h[(size_t)s1 * 128 + lane * 2];
        float2 v2 = *(const float2*)&h[(size_t)s2 * 128 + lane * 2];
        float2 v3 = *(const float2*)&h[(size_t)s3 * 128 + lane * 2];
        a0x = fmaf(w0, v0.x, a0x); a0y = fmaf(w0, v0.y, a0y);
        a1x = fmaf(w1, v1.x, a1x); a1y = fmaf(w1, v1.y, a1y);
        a2x = fmaf(w2, v2.x, a2x); a2y = fmaf(w2, v2.y, a2y);
        a3x = fmaf(w3, v3.x, a3x); a3y = fmaf(w3, v3.y, a3y);
    }
    for (; j < end; j++) {
        int s = csr[j];
        float ww = dis[s];
        float2 v = *(const float2*)&h[(size_t)s * 128 + lane * 2];
        a0x = fmaf(ww, v.x, a0x); a0y = fmaf(ww, v.y, a0y);
    }
    float accx = (a0x + a1x) + (a2x + a3x);
    float accy = (a0y + a1y) + (a2y + a3y);
    float dn = dis[n];
    float2 hv = *(const float2*)&h[(size_t)n * 128 + lane * 2];
    float2 o;
    o.x = fmaxf(dn * (accx + dn * hv.x) + bias[lane * 2], 0.f);
    o.y = fmaxf(dn * (accy + dn * hv.y) + bias[lane * 2 + 1], 0.f);
    *(float2*)&out[(size_t)n * 128 + lane * 2] = o;
}

// one wave per dst node, lanes across 64 features; fused self-loop+bias (no relu)
__global__ __launch_bounds__(256) void gather64(
    const int* __restrict__ rp, const int* __restrict__ csr,
    const float* __restrict__ dis, const float* __restrict__ h,
    const float* __restrict__ bias, float* __restrict__ out, int Nn) {
    int n = (blockIdx.x * 256 + threadIdx.x) >> 6;
    int lane = threadIdx.x & 63;
    if (n >= Nn) return;
    int beg = rp[n], end = rp[n + 1];
    float a0 = 0.f, a1 = 0.f, a2 = 0.f, a3 = 0.f;
    int j = beg;
    for (; j + 3 < end; j += 4) {
        int s0 = csr[j], s1 = csr[j + 1], s2 = csr[j + 2], s3 = csr[j + 3];
        float w0 = dis[s0], w1 = dis[s1], w2 = dis[s2], w3 = dis[s3];
        float v0 = h[(size_t)s0 * 64 + lane];
        float v1 = h[(size_t)s1 * 64 + lane];
        float v2 = h[(size_t)s2 * 64 + lane];
        float v3 = h[(size_t)s3 * 64 + lane];
        a0 = fmaf(w0, v0, a0); a1 = fmaf(w1, v1, a1);
        a2 = fmaf(w2, v2, a2); a3 = fmaf(w3, v3, a3);
    }
    for (; j < end; j++) {
        int s = csr[j];
        a0 = fmaf(dis[s], h[(size_t)s * 64 + lane], a0);
    }
    float acc = (a0 + a1) + (a2 + a3);
    float dn = dis[n];
    float hv = h[(size_t)n * 64 + lane];
    out[(size_t)n * 64 + lane] = dn * (acc + dn * hv) + bias[lane];
}

extern "C" void kernel_launch(void* const* d_in, const int* in_sizes, int n_in,
                              void* d_out, int out_size, void* d_ws, size_t ws_size,
                              hipStream_t stream) {
    const float* x  = (const float*)d_in[0];
    const int*   ei = (const int*)d_in[1];
    const float* W1 = (const float*)d_in[2];
    const float* b1 = (const float*)d_in[3];
    const float* W2 = (const float*)d_in[4];
    const float* b2 = (const float*)d_in[5];

    const int IN = 500, H = 128, OUT = 64;
    const int Nn = in_sizes[0] / IN;     // 50000
    const int E  = in_sizes[1] / 2;      // 800000
    const int* src  = ei;
    const int* dstp = ei + E;

    const int Npad = ((Nn + 63) / 64) * 64;
    const int nb   = (Nn + 255) / 256;
    const int K1p  = 512, K2p = 128;

    // workspace layout (int units)
    int*   degdis  = (int*)d_ws;                 // N: int deg -> float dis in place
    int*   rp      = degdis + Npad;              // N+1
    int*   bsum    = rp + Npad + 64;             // 1024
    int*   boff    = bsum + 1024;                // 1024
    int*   cursor  = boff + 1024;                // N
    int*   csr_src = cursor + Npad;              // E
    unsigned short* Bt1h = (unsigned short*)(csr_src + ((E + 63) / 64) * 64);  // 128*512
    unsigned short* Bt1l = Bt1h + H * K1p;
    unsigned short* Bt2h = Bt1l + H * K1p;       // 64*128
    unsigned short* Bt2l = Bt2h + OUT * K2p;
    float* h1      = (float*)(Bt2l + OUT * K2p);
    float* agg1    = h1 + (size_t)Nn * H;
    float* h2      = h1;                         // reuse after layer-1 gather
    float* dis     = (float*)degdis;
    float* out     = (float*)d_out;

    // ---- degree / CSR build ----
    fill_int<<<(Nn + 255) / 256, 256, 0, stream>>>(degdis, 0, Nn);
    deg_accum_i<<<(E + 255) / 256, 256, 0, stream>>>(dstp, degdis, E);
    scan_part<<<nb, 256, 0, stream>>>(degdis, bsum, Nn);
    scan_top<<<1, 1024, 0, stream>>>(bsum, nb, boff, rp, Nn);
    scan_final<<<nb, 256, 0, stream>>>(degdis, boff, rp, cursor, Nn);
    make_dis<<<(Nn + 255) / 256, 256, 0, stream>>>(degdis, Nn);
    csr_fill<<<(E + 255) / 256, 256, 0, stream>>>(src, dstp, cursor, csr_src, E);

    // ---- weight prep (bf16 hi/lo, transposed) ----
    prep_b<<<(H * K1p + 255) / 256, 256, 0, stream>>>(W1, Bt1h, Bt1l, IN, H, K1p);
    prep_b<<<(OUT * K2p + 255) / 256, 256, 0, stream>>>(W2, Bt2h, Bt2l, H, OUT, K2p);

    // ---- layer 1: 64x128 tile, wave 32x64, KT=16 ----
    gemm_db<64, 128, 16, 2, 2><<<(Nn + 63) / 64, 256, 0, stream>>>(x, Bt1h, Bt1l, h1, Nn, IN, K1p);
    gather128<<<(Nn + 3) / 4, 256, 0, stream>>>(rp, csr_src, dis, h1, b1, agg1, Nn);

    // ---- layer 2: 64x64 tile, wave 32x32, KT=4 ----
    gemm_db<64, 64, 4, 2, 2><<<(Nn + 63) / 64, 256, 0, stream>>>(agg1, Bt2h, Bt2l, h2, Nn, H, K2p);
    gather64<<<(Nn + 3) / 4, 256, 0, stream>>>(rp, csr_src, dis, h2, b2, out, Nn);
}